// Round 2
// baseline (1853.641 us; speedup 1.0000x reference)
//
#include <hip/hip_runtime.h>

typedef __attribute__((ext_vector_type(8))) _Float16 f16x8;
typedef __attribute__((ext_vector_type(16))) float f32x16;

#define B_    8
#define LSEQ  2048
#define DIM   1024
#define QBLK  64
#define KBLK  128
#define DC2   128
#define NKB   (LSEQ / KBLK)   // 16
#define NDC   (DIM / DC2)     // 8
#define NBAND (DIM / 128)     // 8

static __device__ __forceinline__ unsigned pk2(float a, float b) {
    return __builtin_bit_cast(unsigned, __builtin_amdgcn_cvt_pkrtz(a, b));
}

__global__ __launch_bounds__(512, 2)
void coattn(const float* __restrict__ Sp, const float* __restrict__ Dp,
            float* __restrict__ outp)
{
    // XCD swizzle: all 32 q-blocks of one (dir,b) land on one XCD (s % 8 const)
    const int s   = blockIdx.x;
    const int g   = (s & 7) | ((s >> 8) << 3);   // 0..15 = dir*8 + b
    const int qb  = (s >> 3) & 31;
    const int dir = g >> 3;
    const int b   = g & 7;

    const float* Qg = (dir ? Sp : Dp) + (size_t)b * LSEQ * DIM;
    const float* Kg = (dir ? Dp : Sp) + (size_t)b * LSEQ * DIM;
    float* Og = outp + (size_t)dir * ((size_t)B_ * LSEQ * DIM) + (size_t)b * LSEQ * DIM;
    const int q0 = qb * QBLK;

    // single-buffered, every write region barrier-bracketed
    __shared__ unsigned short Klds[KBLK * DC2];   // 32 KB  [k][d] swizzled
    __shared__ unsigned short Qlds[QBLK * DC2];   // 16 KB  [q][d] swizzled
    __shared__ unsigned short Plds[QBLK * KBLK];  // 16 KB  [q][k] swizzled
    __shared__ unsigned short Vlds[128 * KBLK];   // 32 KB  [dcol][k] transposed, swizzled
    __shared__ float redmax[2][4][32];
    __shared__ float redsum[2][4][32];
    __shared__ float alf[QBLK];

    const int t    = threadIdx.x;
    const int lane = t & 63;
    const int w    = t >> 6;
    const int l31  = lane & 31;
    const int hi   = lane >> 5;
    const int ksub = w & 3;      // QK: k-subtile; PV: column tile
    const int qh   = w >> 2;     // q half

    f32x16 O[NBAND];
    #pragma unroll
    for (int i = 0; i < NBAND; ++i)
        #pragma unroll
        for (int r = 0; r < 16; ++r) O[i][r] = 0.0f;

    float m_run = -INFINITY, l_run = 0.0f;

    const int srow = t >> 4;         // 0..31
    const int fcol = (t & 15) << 2;  // 0..60 (float index within 128-col chunk half)
    const int vmm  = t & 31;         // 0..31
    const int vkp0 = t >> 5;         // 0..15

    const int krow = ksub * 32 + l31;
    const int qrow = qh * 32 + l31;

    for (int kb = 0; kb < NKB; ++kb) {
        const int k0g = kb * KBLK;

        // ================= QK^T (scores^T = K . Q^T), 8 chunks of d=128 ====
        f32x16 C;
        #pragma unroll
        for (int r = 0; r < 16; ++r) C[r] = 0.0f;

        float4 kreg[8], qreg[4];
        #pragma unroll
        for (int pass = 0; pass < 4; ++pass)
            #pragma unroll
            for (int h = 0; h < 2; ++h)
                kreg[pass * 2 + h] = *(const float4*)(Kg + (size_t)(k0g + pass * 32 + srow) * DIM + fcol + h * 64);
        #pragma unroll
        for (int pass = 0; pass < 2; ++pass)
            #pragma unroll
            for (int h = 0; h < 2; ++h)
                qreg[pass * 2 + h] = *(const float4*)(Qg + (size_t)(q0 + pass * 32 + srow) * DIM + fcol + h * 64);

        #pragma unroll 1
        for (int dc = 0; dc < NDC; ++dc) {
            __syncthreads();   // all prior readers of Klds/Qlds are done
            #pragma unroll
            for (int pass = 0; pass < 4; ++pass)
                #pragma unroll
                for (int h = 0; h < 2; ++h) {
                    const int row = pass * 32 + srow;
                    const int d   = fcol + h * 64;
                    const float4 v = kreg[pass * 2 + h];
                    *(uint2*)&Klds[row * DC2 + (d ^ ((row & 7) << 3))] =
                        make_uint2(pk2(v.x, v.y), pk2(v.z, v.w));
                }
            #pragma unroll
            for (int pass = 0; pass < 2; ++pass)
                #pragma unroll
                for (int h = 0; h < 2; ++h) {
                    const int row = pass * 32 + srow;
                    const int d   = fcol + h * 64;
                    const float4 v = qreg[pass * 2 + h];
                    *(uint2*)&Qlds[row * DC2 + (d ^ ((row & 7) << 3))] =
                        make_uint2(pk2(v.x, v.y), pk2(v.z, v.w));
                }
            __syncthreads();   // writes visible to all
            if (dc + 1 < NDC) {   // prefetch next chunk; in flight across this phase's MFMAs
                const int dbase = (dc + 1) * DC2;
                #pragma unroll
                for (int pass = 0; pass < 4; ++pass)
                    #pragma unroll
                    for (int h = 0; h < 2; ++h)
                        kreg[pass * 2 + h] = *(const float4*)(Kg + (size_t)(k0g + pass * 32 + srow) * DIM + dbase + fcol + h * 64);
                #pragma unroll
                for (int pass = 0; pass < 2; ++pass)
                    #pragma unroll
                    for (int h = 0; h < 2; ++h)
                        qreg[pass * 2 + h] = *(const float4*)(Qg + (size_t)(q0 + pass * 32 + srow) * DIM + dbase + fcol + h * 64);
            }
            #pragma unroll
            for (int kc = 0; kc < 8; ++kc) {
                const int d0 = kc * 16 + hi * 8;
                f16x8 a  = *(const f16x8*)&Klds[krow * DC2 + (d0 ^ ((krow & 7) << 3))];
                f16x8 bq = *(const f16x8*)&Qlds[qrow * DC2 + (d0 ^ ((qrow & 7) << 3))];
                C = __builtin_amdgcn_mfma_f32_32x32x16_f16(a, bq, C, 0, 0, 0);
            }
        }

        // ================= online softmax =================
        // lane holds C[r] at (k = 32*ksub + crow(r,hi), q = 32*qh + l31)
        float rm = -INFINITY;
        #pragma unroll
        for (int r = 0; r < 16; ++r) rm = fmaxf(rm, C[r]);
        rm = fmaxf(rm, __shfl_xor(rm, 32));
        if (lane < 32) redmax[qh][ksub][l31] = rm;
        __syncthreads();

        const float bm = fmaxf(fmaxf(redmax[qh][0][l31], redmax[qh][1][l31]),
                               fmaxf(redmax[qh][2][l31], redmax[qh][3][l31]));
        const float mn = fmaxf(m_run, bm);
        const float al = __expf(m_run - mn);
        float p[16];
        float ps = 0.0f;
        #pragma unroll
        for (int r = 0; r < 16; ++r) { p[r] = __expf(C[r] - mn); ps += p[r]; }
        ps += __shfl_xor(ps, 32);
        if (lane < 32) {
            redsum[qh][ksub][l31] = ps;
            if (ksub == 0) alf[qh * 32 + l31] = al;
        }
        {   // write P (fp16) to LDS [q][k]
            #pragma unroll
            for (int rp = 0; rp < 8; ++rp) {
                const int r  = rp * 2;
                const int kk = ksub * 32 + (r & 3) + 8 * (r >> 2) + 4 * hi;
                *(unsigned*)&Plds[qrow * KBLK + (kk ^ ((qrow & 7) << 3))] = pk2(p[r], p[r + 1]);
            }
        }
        __syncthreads();

        const float bs = redsum[qh][0][l31] + redsum[qh][1][l31] +
                         redsum[qh][2][l31] + redsum[qh][3][l31];
        l_run = l_run * al + bs;
        m_run = mn;

        float alr[16];
        #pragma unroll
        for (int r = 0; r < 16; ++r)
            alr[r] = alf[qh * 32 + (r & 3) + 8 * (r >> 2) + 4 * hi];
        #pragma unroll
        for (int i = 0; i < NBAND; ++i)
            #pragma unroll
            for (int r = 0; r < 16; ++r) O[i][r] *= alr[r];

        // P A-frags: load once, reuse across all 8 bands
        f16x8 pa[8];
        #pragma unroll
        for (int kc = 0; kc < 8; ++kc) {
            const int kk0 = kc * 16 + hi * 8;
            pa[kc] = *(const f16x8*)&Plds[qrow * KBLK + (kk0 ^ ((qrow & 7) << 3))];
        }

        // ================= PV (O += P . V), 8 bands of 128 cols ============
        float4 v0s[4], v1s[4];
        #pragma unroll
        for (int pass = 0; pass < 4; ++pass) {
            const int kp = pass * 16 + vkp0;
            v0s[pass] = *(const float4*)(Kg + (size_t)(k0g + 2 * kp) * DIM + vmm * 4);
            v1s[pass] = *(const float4*)(Kg + (size_t)(k0g + 2 * kp + 1) * DIM + vmm * 4);
        }

        #pragma unroll
        for (int band = 0; band < NBAND; ++band) {
            __syncthreads();   // prior readers of Vlds done
            #pragma unroll
            for (int pass = 0; pass < 4; ++pass) {
                const int kp = pass * 16 + vkp0;
                const float* a0 = (const float*)&v0s[pass];
                const float* a1 = (const float*)&v1s[pass];
                #pragma unroll
                for (int j = 0; j < 4; ++j) {
                    const int dcl = vmm * 4 + j;
                    *(unsigned*)&Vlds[dcl * KBLK + ((2 * kp) ^ ((dcl & 7) << 3))] = pk2(a0[j], a1[j]);
                }
            }
            __syncthreads();   // writes visible
            if (band + 1 < NBAND) {   // prefetch next band; in flight across MFMAs
                const int cb = (band + 1) * 128;
                #pragma unroll
                for (int pass = 0; pass < 4; ++pass) {
                    const int kp = pass * 16 + vkp0;
                    v0s[pass] = *(const float4*)(Kg + (size_t)(k0g + 2 * kp) * DIM + cb + vmm * 4);
                    v1s[pass] = *(const float4*)(Kg + (size_t)(k0g + 2 * kp + 1) * DIM + cb + vmm * 4);
                }
            }
            const int dcl = ksub * 32 + l31;
            const int sw  = (dcl & 7) << 3;
            #pragma unroll
            for (int kc = 0; kc < 8; ++kc) {
                const int kk0 = kc * 16 + hi * 8;
                f16x8 vb = *(const f16x8*)&Vlds[dcl * KBLK + (kk0 ^ sw)];
                O[band] = __builtin_amdgcn_mfma_f32_32x32x16_f16(pa[kc], vb, O[band], 0, 0, 0);
            }
        }
    }

    // ================= epilogue: out = residual(Q) + O / l =================
    if (lane < 32 && ksub == 0) alf[qh * 32 + l31] = 1.0f / l_run;
    __syncthreads();
    #pragma unroll
    for (int r = 0; r < 16; ++r) {
        const int qr = qh * 32 + (r & 3) + 8 * (r >> 2) + 4 * hi;
        const float il = alf[qr];
        const size_t rowoff = (size_t)(q0 + qr) * DIM;
        #pragma unroll
        for (int band = 0; band < NBAND; ++band) {
            const int dcol = band * 128 + ksub * 32 + l31;
            Og[rowoff + dcol] = Qg[rowoff + dcol] + O[band][r] * il;
        }
    }
}

extern "C" void kernel_launch(void* const* d_in, const int* in_sizes, int n_in,
                              void* d_out, int out_size, void* d_ws, size_t ws_size,
                              hipStream_t stream) {
    const float* S = (const float*)d_in[0];
    const float* D = (const float*)d_in[1];
    float* out = (float*)d_out;
    coattn<<<dim3(512, 1, 1), dim3(512, 1, 1), 0, stream>>>(S, D, out);
}

// Round 3
// 768.340 us; speedup vs baseline: 2.4125x; 2.4125x over previous
//
#include <hip/hip_runtime.h>

typedef __attribute__((ext_vector_type(8))) _Float16 f16x8;
typedef __attribute__((ext_vector_type(16))) float f32x16;

#define B_    8
#define LSEQ  2048
#define DIM   1024
#define QBLK  64
#define KBLK  128
#define NKB   (LSEQ / KBLK)   // 16
#define NDC   (DIM / 128)     // 8
#define NBAND (DIM / 128)     // 8

// K/V image geometry: 32KB tiles (128x128 fp16, swizzle baked in)
#define TILE_US   16384        // ushorts per tile
#define KIMG_US   ((size_t)2 * 8 * 16 * 8 * TILE_US)   // 64 MB
#define WS_NEED   ((size_t)2 * KIMG_US * 2)            // 128 MB (K + V images, bytes)

static __device__ __forceinline__ unsigned pk2(float a, float b) {
    return __builtin_bit_cast(unsigned, __builtin_amdgcn_cvt_pkrtz(a, b));
}

#define VMCNT(n) asm volatile("s_waitcnt vmcnt(" #n ")" ::: "memory")

static __device__ __forceinline__ void gll16(const void* g, void* l) {
    __builtin_amdgcn_global_load_lds(
        (const __attribute__((address_space(1))) void*)g,
        (__attribute__((address_space(3))) void*)l, 16, 0, 0);
}

// stage a 32KB tile: 8 waves x 4 ops x 1KB (lane*16 dest offset added by HW)
static __device__ __forceinline__ void issue32(const unsigned short* gt, unsigned short* lb, int w, int lane) {
    #pragma unroll
    for (int j = 0; j < 4; ++j) {
        const int off = (w * 4 + j) * 1024;
        gll16((const char*)gt + off + lane * 16, (char*)lb + off);
    }
}
// stage a 16KB tile: 8 waves x 2 ops x 1KB
static __device__ __forceinline__ void issue16(const unsigned short* gt, unsigned short* lb, int w, int lane) {
    #pragma unroll
    for (int j = 0; j < 2; ++j) {
        const int off = (w * 2 + j) * 1024;
        gll16((const char*)gt + off + lane * 16, (char*)lb + off);
    }
}

// ============ prepass: fp32 -> fp16 swizzled LDS-image tiles ============
// Kimg tile (m,b,kb,dc): elem (r,c) at r*128 + (c ^ ((r&7)<<3))     [k][d]
// Vimg tile (m,b,band,kb): elem (dcl,kk) at dcl*128 + (kk ^ ((dcl&7)<<3))  [d][k]
__global__ __launch_bounds__(256)
void prepass(const float* __restrict__ Sp, const float* __restrict__ Dp,
             unsigned short* __restrict__ Kimg, unsigned short* __restrict__ Vimg)
{
    const int blk = blockIdx.x;            // 2*8*16*8 = 2048
    const int dc = blk & 7;
    const int kb = (blk >> 3) & 15;
    const int b  = (blk >> 7) & 7;
    const int m  = blk >> 10;
    const float* src = (m ? Dp : Sp) + ((size_t)b * LSEQ + kb * 128) * DIM + dc * 128;
    unsigned short* kt = Kimg + (size_t)((((m * 8 + b) * 16 + kb) * 8) + dc) * TILE_US;
    unsigned short* vt = Vimg + (size_t)((((m * 8 + b) * 8 + dc) * 16) + kb) * TILE_US;

    __shared__ unsigned short tile[128 * 132];
    const int t = threadIdx.x;

    #pragma unroll
    for (int i = 0; i < 16; ++i) {
        const int idx = t + i * 256;
        const int r = idx >> 5;
        const int c4 = (idx & 31) << 2;
        const float4 v = *(const float4*)(src + (size_t)r * DIM + c4);
        const unsigned lo = pk2(v.x, v.y), hi2 = pk2(v.z, v.w);
        *(uint2*)(kt + r * 128 + (c4 ^ ((r & 7) << 3))) = make_uint2(lo, hi2);
        *(uint2*)(&tile[r * 132 + c4]) = make_uint2(lo, hi2);
    }
    __syncthreads();
    #pragma unroll
    for (int i = 0; i < 32; ++i) {
        const int widx = t + i * 256;
        const int dcl = widx >> 6;
        const int wk  = widx & 63;     // kk = wk*2
        const unsigned a  = tile[(wk * 2) * 132 + dcl];
        const unsigned bb = tile[(wk * 2 + 1) * 132 + dcl];
        ((unsigned*)vt)[dcl * 64 + (wk ^ ((dcl & 7) << 2))] = a | (bb << 16);
    }
}

// ============ main flash kernel: gll staging + counted vmcnt ============
__global__ __launch_bounds__(512, 2)
void coattn_main(const float* __restrict__ Sp, const float* __restrict__ Dp,
                 float* __restrict__ outp,
                 const unsigned short* __restrict__ Kimg,
                 const unsigned short* __restrict__ Vimg)
{
    const int s   = blockIdx.x;
    const int g   = (s & 7) | ((s >> 8) << 3);
    const int qb  = (s >> 3) & 31;
    const int dir = g >> 3;
    const int b   = g & 7;
    const int mat_k = dir;          // dir0: K=S(0); dir1: K=D(1)
    const int mat_q = 1 - dir;

    const float* Qg = (dir ? Sp : Dp) + (size_t)b * LSEQ * DIM;   // residual (fp32)
    float* Og = outp + (size_t)dir * ((size_t)B_ * LSEQ * DIM) + (size_t)b * LSEQ * DIM;
    const int q0 = qb * QBLK;

    const unsigned short* kbase = Kimg + (size_t)(mat_k * 8 + b) * 16 * 8 * TILE_US;
    const unsigned short* qbase = Kimg + (size_t)(mat_q * 8 + b) * 16 * 8 * TILE_US
                                + (size_t)(qb >> 1) * 8 * TILE_US + (size_t)(qb & 1) * 8192;
    const unsigned short* vbase = Vimg + (size_t)(mat_k * 8 + b) * 8 * 16 * TILE_US;

    __shared__ unsigned short KV0[128 * 128];   // 32 KB (K chunks even / V bands even)
    __shared__ unsigned short KV1[128 * 128];   // 32 KB
    __shared__ unsigned short Qb0[64 * 128];    // 16 KB
    __shared__ unsigned short Qb1[64 * 128];    // 16 KB
    __shared__ unsigned short Plds[QBLK * KBLK];
    __shared__ float redmax[2][4][32];
    __shared__ float redsum[2][4][32];
    __shared__ float alf[QBLK];

    const int t    = threadIdx.x;
    const int lane = t & 63;
    const int w    = t >> 6;
    const int l31  = lane & 31;
    const int hi   = lane >> 5;
    const int ksub = w & 3;
    const int qh   = w >> 2;

    const int krow = ksub * 32 + l31;
    const int qrow = qh * 32 + l31;
    const int kswz = (krow & 7) << 3;
    const int qswz = (qrow & 7) << 3;

    f32x16 O[NBAND];
    #pragma unroll
    for (int i = 0; i < NBAND; ++i)
        #pragma unroll
        for (int r = 0; r < 16; ++r) O[i][r] = 0.0f;

    float m_run = -INFINITY, l_run = 0.0f;

    for (int kb = 0; kb < NKB; ++kb) {
        const unsigned short* kt = kbase + (size_t)kb * 8 * TILE_US;

        // ---- QK^T: 8 d-chunks, 2-deep pipeline ----
        f32x16 C;
        #pragma unroll
        for (int r = 0; r < 16; ++r) C[r] = 0.0f;

        issue32(kt + 0 * TILE_US, KV0, w, lane);
        issue16(qbase + 0 * TILE_US, Qb0, w, lane);
        issue32(kt + 1 * TILE_US, KV1, w, lane);
        issue16(qbase + 1 * TILE_US, Qb1, w, lane);
        VMCNT(6);
        __syncthreads();

        #pragma unroll
        for (int dc = 0; dc < NDC; ++dc) {
            const unsigned short* Kb = (dc & 1) ? KV1 : KV0;
            const unsigned short* Qb = (dc & 1) ? Qb1 : Qb0;
            #pragma unroll
            for (int kc = 0; kc < 8; ++kc) {
                const int d0 = kc * 16 + hi * 8;
                f16x8 a  = *(const f16x8*)&Kb[krow * 128 + (d0 ^ kswz)];
                f16x8 bq = *(const f16x8*)&Qb[qrow * 128 + (d0 ^ qswz)];
                C = __builtin_amdgcn_mfma_f32_32x32x16_f16(a, bq, C, 0, 0, 0);
            }
            __syncthreads();   // all waves done reading buf[dc&1]
            if (dc + 2 < NDC) {
                unsigned short* kd = (dc & 1) ? KV1 : KV0;
                unsigned short* qd = (dc & 1) ? Qb1 : Qb0;
                issue32(kt + (dc + 2) * TILE_US, kd, w, lane);
                issue16(qbase + (dc + 2) * TILE_US, qd, w, lane);
                VMCNT(6);      // chunk dc+1 complete
            } else if (dc == NDC - 2) {
                VMCNT(0);      // chunk 7 complete
            }
            __syncthreads();
        }

        // ---- online softmax (lane holds C[r] at k=32*ksub+crow(r,hi), q=32*qh+l31) ----
        float rm = -INFINITY;
        #pragma unroll
        for (int r = 0; r < 16; ++r) rm = fmaxf(rm, C[r]);
        rm = fmaxf(rm, __shfl_xor(rm, 32));
        if (lane < 32) redmax[qh][ksub][l31] = rm;
        __syncthreads();

        // V bands 0,1 DMA in flight under softmax VALU (KV bufs free: QK reads done)
        issue32(vbase + (size_t)(0 * 16 + kb) * TILE_US, KV0, w, lane);
        issue32(vbase + (size_t)(1 * 16 + kb) * TILE_US, KV1, w, lane);

        const float bm = fmaxf(fmaxf(redmax[qh][0][l31], redmax[qh][1][l31]),
                               fmaxf(redmax[qh][2][l31], redmax[qh][3][l31]));
        const float mn = fmaxf(m_run, bm);
        const float al = __expf(m_run - mn);
        float p[16];
        float ps = 0.0f;
        #pragma unroll
        for (int r = 0; r < 16; ++r) { p[r] = __expf(C[r] - mn); ps += p[r]; }
        ps += __shfl_xor(ps, 32);
        if (lane < 32) {
            redsum[qh][ksub][l31] = ps;
            if (ksub == 0) alf[qh * 32 + l31] = al;
        }
        {   // P (fp16) -> LDS [q][k]
            #pragma unroll
            for (int rp = 0; rp < 8; ++rp) {
                const int r  = rp * 2;
                const int kk = ksub * 32 + (r & 3) + 8 * (r >> 2) + 4 * hi;
                *(unsigned*)&Plds[qrow * KBLK + (kk ^ qswz)] = pk2(p[r], p[r + 1]);
            }
        }
        __syncthreads();

        const float bs = redsum[qh][0][l31] + redsum[qh][1][l31] +
                         redsum[qh][2][l31] + redsum[qh][3][l31];
        l_run = l_run * al + bs;
        m_run = mn;

        float alr[16];
        #pragma unroll
        for (int r = 0; r < 16; ++r)
            alr[r] = alf[qh * 32 + (r & 3) + 8 * (r >> 2) + 4 * hi];
        #pragma unroll
        for (int i = 0; i < NBAND; ++i)
            #pragma unroll
            for (int r = 0; r < 16; ++r) O[i][r] *= alr[r];

        f16x8 pa[8];
        #pragma unroll
        for (int kc = 0; kc < 8; ++kc) {
            const int kk0 = kc * 16 + hi * 8;
            pa[kc] = *(const f16x8*)&Plds[qrow * KBLK + (kk0 ^ qswz)];
        }

        VMCNT(4);          // band 0 complete (band 1 still in flight)
        __syncthreads();

        // ---- PV: 8 bands, 2-deep pipeline ----
        const int dcl = ksub * 32 + l31;
        const int vswz = (dcl & 7) << 3;
        #pragma unroll
        for (int band = 0; band < NBAND; ++band) {
            const unsigned short* Vb = (band & 1) ? KV1 : KV0;
            #pragma unroll
            for (int kc = 0; kc < 8; ++kc) {
                const int kk0 = kc * 16 + hi * 8;
                f16x8 vb = *(const f16x8*)&Vb[dcl * 128 + (kk0 ^ vswz)];
                O[band] = __builtin_amdgcn_mfma_f32_32x32x16_f16(pa[kc], vb, O[band], 0, 0, 0);
            }
            __syncthreads();
            if (band + 2 < NBAND) {
                unsigned short* vd = (band & 1) ? KV1 : KV0;
                issue32(vbase + (size_t)((band + 2) * 16 + kb) * TILE_US, vd, w, lane);
                VMCNT(4);
            } else if (band == NBAND - 2) {
                VMCNT(0);
            }
            __syncthreads();
        }
    }

    // ---- epilogue: out = residual(Q) + O / l ----
    if (lane < 32 && ksub == 0) alf[qh * 32 + l31] = 1.0f / l_run;
    __syncthreads();
    #pragma unroll
    for (int r = 0; r < 16; ++r) {
        const int qr = qh * 32 + (r & 3) + 8 * (r >> 2) + 4 * hi;
        const float il = alf[qr];
        const size_t rowoff = (size_t)(q0 + qr) * DIM;
        #pragma unroll
        for (int band = 0; band < NBAND; ++band) {
            const int dcol = band * 128 + ksub * 32 + l31;
            Og[rowoff + dcol] = Qg[rowoff + dcol] + O[band][r] * il;
        }
    }
}

// ============ fallback (round-2 kernel, verbatim — used if ws too small) ============
__global__ __launch_bounds__(512, 2)
void coattn_fb(const float* __restrict__ Sp, const float* __restrict__ Dp,
               float* __restrict__ outp)
{
    const int s   = blockIdx.x;
    const int g   = (s & 7) | ((s >> 8) << 3);
    const int qb  = (s >> 3) & 31;
    const int dir = g >> 3;
    const int b   = g & 7;

    const float* Qg = (dir ? Sp : Dp) + (size_t)b * LSEQ * DIM;
    const float* Kg = (dir ? Dp : Sp) + (size_t)b * LSEQ * DIM;
    float* Og = outp + (size_t)dir * ((size_t)B_ * LSEQ * DIM) + (size_t)b * LSEQ * DIM;
    const int q0 = qb * QBLK;

    __shared__ unsigned short Klds[KBLK * 128];
    __shared__ unsigned short Qlds[QBLK * 128];
    __shared__ unsigned short Plds[QBLK * KBLK];
    __shared__ unsigned short Vlds[128 * KBLK];
    __shared__ float redmax[2][4][32];
    __shared__ float redsum[2][4][32];
    __shared__ float alf[QBLK];

    const int t    = threadIdx.x;
    const int lane = t & 63;
    const int w    = t >> 6;
    const int l31  = lane & 31;
    const int hi   = lane >> 5;
    const int ksub = w & 3;
    const int qh   = w >> 2;

    f32x16 O[NBAND];
    #pragma unroll
    for (int i = 0; i < NBAND; ++i)
        #pragma unroll
        for (int r = 0; r < 16; ++r) O[i][r] = 0.0f;

    float m_run = -INFINITY, l_run = 0.0f;

    const int srow = t >> 4;
    const int fcol = (t & 15) << 2;
    const int vmm  = t & 31;
    const int vkp0 = t >> 5;

    const int krow = ksub * 32 + l31;
    const int qrow = qh * 32 + l31;

    for (int kb = 0; kb < NKB; ++kb) {
        const int k0g = kb * KBLK;
        f32x16 C;
        #pragma unroll
        for (int r = 0; r < 16; ++r) C[r] = 0.0f;

        float4 kreg[8], qreg[4];
        #pragma unroll
        for (int pass = 0; pass < 4; ++pass)
            #pragma unroll
            for (int h = 0; h < 2; ++h)
                kreg[pass * 2 + h] = *(const float4*)(Kg + (size_t)(k0g + pass * 32 + srow) * DIM + fcol + h * 64);
        #pragma unroll
        for (int pass = 0; pass < 2; ++pass)
            #pragma unroll
            for (int h = 0; h < 2; ++h)
                qreg[pass * 2 + h] = *(const float4*)(Qg + (size_t)(q0 + pass * 32 + srow) * DIM + fcol + h * 64);

        #pragma unroll 1
        for (int dc = 0; dc < NDC; ++dc) {
            __syncthreads();
            #pragma unroll
            for (int pass = 0; pass < 4; ++pass)
                #pragma unroll
                for (int h = 0; h < 2; ++h) {
                    const int row = pass * 32 + srow;
                    const int d   = fcol + h * 64;
                    const float4 v = kreg[pass * 2 + h];
                    *(uint2*)&Klds[row * 128 + (d ^ ((row & 7) << 3))] =
                        make_uint2(pk2(v.x, v.y), pk2(v.z, v.w));
                }
            #pragma unroll
            for (int pass = 0; pass < 2; ++pass)
                #pragma unroll
                for (int h = 0; h < 2; ++h) {
                    const int row = pass * 32 + srow;
                    const int d   = fcol + h * 64;
                    const float4 v = qreg[pass * 2 + h];
                    *(uint2*)&Qlds[row * 128 + (d ^ ((row & 7) << 3))] =
                        make_uint2(pk2(v.x, v.y), pk2(v.z, v.w));
                }
            __syncthreads();
            if (dc + 1 < NDC) {
                const int dbase = (dc + 1) * 128;
                #pragma unroll
                for (int pass = 0; pass < 4; ++pass)
                    #pragma unroll
                    for (int h = 0; h < 2; ++h)
                        kreg[pass * 2 + h] = *(const float4*)(Kg + (size_t)(k0g + pass * 32 + srow) * DIM + dbase + fcol + h * 64);
                #pragma unroll
                for (int pass = 0; pass < 2; ++pass)
                    #pragma unroll
                    for (int h = 0; h < 2; ++h)
                        qreg[pass * 2 + h] = *(const float4*)(Qg + (size_t)(q0 + pass * 32 + srow) * DIM + dbase + fcol + h * 64);
            }
            #pragma unroll
            for (int kc = 0; kc < 8; ++kc) {
                const int d0 = kc * 16 + hi * 8;
                f16x8 a  = *(const f16x8*)&Klds[krow * 128 + (d0 ^ ((krow & 7) << 3))];
                f16x8 bq = *(const f16x8*)&Qlds[qrow * 128 + (d0 ^ ((qrow & 7) << 3))];
                C = __builtin_amdgcn_mfma_f32_32x32x16_f16(a, bq, C, 0, 0, 0);
            }
        }

        float rm = -INFINITY;
        #pragma unroll
        for (int r = 0; r < 16; ++r) rm = fmaxf(rm, C[r]);
        rm = fmaxf(rm, __shfl_xor(rm, 32));
        if (lane < 32) redmax[qh][ksub][l31] = rm;
        __syncthreads();

        const float bm = fmaxf(fmaxf(redmax[qh][0][l31], redmax[qh][1][l31]),
                               fmaxf(redmax[qh][2][l31], redmax[qh][3][l31]));
        const float mn = fmaxf(m_run, bm);
        const float al = __expf(m_run - mn);
        float p[16];
        float ps = 0.0f;
        #pragma unroll
        for (int r = 0; r < 16; ++r) { p[r] = __expf(C[r] - mn); ps += p[r]; }
        ps += __shfl_xor(ps, 32);
        if (lane < 32) {
            redsum[qh][ksub][l31] = ps;
            if (ksub == 0) alf[qh * 32 + l31] = al;
        }
        {
            #pragma unroll
            for (int rp = 0; rp < 8; ++rp) {
                const int r  = rp * 2;
                const int kk = ksub * 32 + (r & 3) + 8 * (r >> 2) + 4 * hi;
                *(unsigned*)&Plds[qrow * KBLK + (kk ^ ((qrow & 7) << 3))] = pk2(p[r], p[r + 1]);
            }
        }
        __syncthreads();

        const float bs = redsum[qh][0][l31] + redsum[qh][1][l31] +
                         redsum[qh][2][l31] + redsum[qh][3][l31];
        l_run = l_run * al + bs;
        m_run = mn;

        float alr[16];
        #pragma unroll
        for (int r = 0; r < 16; ++r)
            alr[r] = alf[qh * 32 + (r & 3) + 8 * (r >> 2) + 4 * hi];
        #pragma unroll
        for (int i = 0; i < NBAND; ++i)
            #pragma unroll
            for (int r = 0; r < 16; ++r) O[i][r] *= alr[r];

        f16x8 pa[8];
        #pragma unroll
        for (int kc = 0; kc < 8; ++kc) {
            const int kk0 = kc * 16 + hi * 8;
            pa[kc] = *(const f16x8*)&Plds[qrow * KBLK + (kk0 ^ ((qrow & 7) << 3))];
        }

        float4 v0s[4], v1s[4];
        #pragma unroll
        for (int pass = 0; pass < 4; ++pass) {
            const int kp = pass * 16 + vkp0;
            v0s[pass] = *(const float4*)(Kg + (size_t)(k0g + 2 * kp) * DIM + vmm * 4);
            v1s[pass] = *(const float4*)(Kg + (size_t)(k0g + 2 * kp + 1) * DIM + vmm * 4);
        }

        #pragma unroll
        for (int band = 0; band < NBAND; ++band) {
            __syncthreads();
            #pragma unroll
            for (int pass = 0; pass < 4; ++pass) {
                const int kp = pass * 16 + vkp0;
                const float* a0 = (const float*)&v0s[pass];
                const float* a1 = (const float*)&v1s[pass];
                #pragma unroll
                for (int j = 0; j < 4; ++j) {
                    const int dcl = vmm * 4 + j;
                    *(unsigned*)&Vlds[dcl * KBLK + ((2 * kp) ^ ((dcl & 7) << 3))] = pk2(a0[j], a1[j]);
                }
            }
            __syncthreads();
            if (band + 1 < NBAND) {
                const int cb = (band + 1) * 128;
                #pragma unroll
                for (int pass = 0; pass < 4; ++pass) {
                    const int kp = pass * 16 + vkp0;
                    v0s[pass] = *(const float4*)(Kg + (size_t)(k0g + 2 * kp) * DIM + cb + vmm * 4);
                    v1s[pass] = *(const float4*)(Kg + (size_t)(k0g + 2 * kp + 1) * DIM + cb + vmm * 4);
                }
            }
            const int dcl = ksub * 32 + l31;
            const int sw  = (dcl & 7) << 3;
            #pragma unroll
            for (int kc = 0; kc < 8; ++kc) {
                const int kk0 = kc * 16 + hi * 8;
                f16x8 vb = *(const f16x8*)&Vlds[dcl * KBLK + (kk0 ^ sw)];
                O[band] = __builtin_amdgcn_mfma_f32_32x32x16_f16(pa[kc], vb, O[band], 0, 0, 0);
            }
        }
    }

    if (lane < 32 && ksub == 0) alf[qh * 32 + l31] = 1.0f / l_run;
    __syncthreads();
    #pragma unroll
    for (int r = 0; r < 16; ++r) {
        const int qr = qh * 32 + (r & 3) + 8 * (r >> 2) + 4 * hi;
        const float il = alf[qr];
        const size_t rowoff = (size_t)(q0 + qr) * DIM;
        #pragma unroll
        for (int band = 0; band < NBAND; ++band) {
            const int dcol = band * 128 + ksub * 32 + l31;
            Og[rowoff + dcol] = Qg[rowoff + dcol] + O[band][r] * il;
        }
    }
}

extern "C" void kernel_launch(void* const* d_in, const int* in_sizes, int n_in,
                              void* d_out, int out_size, void* d_ws, size_t ws_size,
                              hipStream_t stream) {
    const float* S = (const float*)d_in[0];
    const float* D = (const float*)d_in[1];
    float* out = (float*)d_out;
    if (ws_size >= WS_NEED) {
        unsigned short* Kimg = (unsigned short*)d_ws;
        unsigned short* Vimg = Kimg + KIMG_US;
        prepass<<<dim3(2048, 1, 1), dim3(256, 1, 1), 0, stream>>>(S, D, Kimg, Vimg);
        coattn_main<<<dim3(512, 1, 1), dim3(512, 1, 1), 0, stream>>>(S, D, out, Kimg, Vimg);
    } else {
        coattn_fb<<<dim3(512, 1, 1), dim3(512, 1, 1), 0, stream>>>(S, D, out);
    }
}

// Round 4
// 644.722 us; speedup vs baseline: 2.8751x; 1.1917x over previous
//
#include <hip/hip_runtime.h>

typedef __attribute__((ext_vector_type(8))) _Float16 f16x8;
typedef __attribute__((ext_vector_type(16))) float f32x16;

#define B_    8
#define LSEQ  2048
#define DIM   1024
#define QBLK  64
#define KBLK  128
#define NKB   (LSEQ / KBLK)   // 16
#define NDC   (DIM / 128)     // 8
#define NBAND (DIM / 128)     // 8

// K/V image geometry: 32KB tiles (128x128 fp16, swizzle baked in)
#define TILE_US   16384        // ushorts per tile
#define KIMG_US   ((size_t)2 * 8 * 16 * 8 * TILE_US)   // 64 MB
#define WS_NEED   ((size_t)2 * KIMG_US * 2)            // 128 MB

static __device__ __forceinline__ unsigned pk2(float a, float b) {
    return __builtin_bit_cast(unsigned, __builtin_amdgcn_cvt_pkrtz(a, b));
}

#define VMCNT(n) asm volatile("s_waitcnt vmcnt(" #n ")" ::: "memory")
#define BAR()    do { asm volatile("" ::: "memory"); __builtin_amdgcn_s_barrier(); \
                      asm volatile("" ::: "memory"); } while (0)

static __device__ __forceinline__ void gll16(const void* g, void* l) {
    __builtin_amdgcn_global_load_lds(
        (const __attribute__((address_space(1))) void*)g,
        (__attribute__((address_space(3))) void*)l, 16, 0, 0);
}

// 32KB tile: 8 waves x 4 ops x 1KB ; 16KB tile: 8 waves x 2 ops x 1KB
static __device__ __forceinline__ void issue32(const unsigned short* gt, unsigned short* lb, int w, int lane) {
    #pragma unroll
    for (int j = 0; j < 4; ++j) {
        const int off = (w * 4 + j) * 1024;
        gll16((const char*)gt + off + lane * 16, (char*)lb + off);
    }
}
static __device__ __forceinline__ void issue16(const unsigned short* gt, unsigned short* lb, int w, int lane) {
    #pragma unroll
    for (int j = 0; j < 2; ++j) {
        const int off = (w * 2 + j) * 1024;
        gll16((const char*)gt + off + lane * 16, (char*)lb + off);
    }
}

// ============ prepass: fp32 -> fp16 swizzled LDS-image tiles (unchanged R3) ============
__global__ __launch_bounds__(256)
void prepass(const float* __restrict__ Sp, const float* __restrict__ Dp,
             unsigned short* __restrict__ Kimg, unsigned short* __restrict__ Vimg)
{
    const int blk = blockIdx.x;            // 2*8*16*8 = 2048
    const int dc = blk & 7;
    const int kb = (blk >> 3) & 15;
    const int b  = (blk >> 7) & 7;
    const int m  = blk >> 10;
    const float* src = (m ? Dp : Sp) + ((size_t)b * LSEQ + kb * 128) * DIM + dc * 128;
    unsigned short* kt = Kimg + (size_t)((((m * 8 + b) * 16 + kb) * 8) + dc) * TILE_US;
    unsigned short* vt = Vimg + (size_t)((((m * 8 + b) * 8 + dc) * 16) + kb) * TILE_US;

    __shared__ unsigned short tile[128 * 132];
    const int t = threadIdx.x;

    #pragma unroll
    for (int i = 0; i < 16; ++i) {
        const int idx = t + i * 256;
        const int r = idx >> 5;
        const int c4 = (idx & 31) << 2;
        const float4 v = *(const float4*)(src + (size_t)r * DIM + c4);
        const unsigned lo = pk2(v.x, v.y), hi2 = pk2(v.z, v.w);
        *(uint2*)(kt + r * 128 + (c4 ^ ((r & 7) << 3))) = make_uint2(lo, hi2);
        *(uint2*)(&tile[r * 132 + c4]) = make_uint2(lo, hi2);
    }
    __syncthreads();
    #pragma unroll
    for (int i = 0; i < 32; ++i) {
        const int widx = t + i * 256;
        const int dcl = widx >> 6;
        const int wk  = widx & 63;
        const unsigned a  = tile[(wk * 2) * 132 + dcl];
        const unsigned bb = tile[(wk * 2 + 1) * 132 + dcl];
        ((unsigned*)vt)[dcl * 64 + (wk ^ ((dcl & 7) << 2))] = a | (bb << 16);
    }
}

// ============ main: 16-phase/kb ring pipeline, raw barriers, counted vmcnt ============
__global__ __launch_bounds__(512, 2)
void coattn_main(const float* __restrict__ Sp, const float* __restrict__ Dp,
                 float* __restrict__ outp,
                 const unsigned short* __restrict__ Kimg,
                 const unsigned short* __restrict__ Vimg)
{
    const int s   = blockIdx.x;
    const int g   = (s & 7) | ((s >> 8) << 3);
    const int qb  = (s >> 3) & 31;
    const int dir = g >> 3;
    const int b   = g & 7;
    const int mat_k = dir;
    const int mat_q = 1 - dir;

    const float* Qg = (dir ? Sp : Dp) + (size_t)b * LSEQ * DIM;
    float* Og = outp + (size_t)dir * ((size_t)B_ * LSEQ * DIM) + (size_t)b * LSEQ * DIM;
    const int q0 = qb * QBLK;

    const unsigned short* kbase = Kimg + (size_t)(mat_k * 8 + b) * 16 * 8 * TILE_US;
    const unsigned short* qbase = Kimg + (size_t)(mat_q * 8 + b) * 16 * 8 * TILE_US
                                + (size_t)(qb >> 1) * 8 * TILE_US + (size_t)(qb & 1) * 8192;
    const unsigned short* vbase = Vimg + (size_t)(mat_k * 8 + b) * 8 * 16 * TILE_US;

    __shared__ unsigned short Rr[3][16384];   // 96 KB: K-chunks / V-bands ring
    __shared__ unsigned short QR_[3][8192];   // 48 KB: Q-chunks ring (slot0 reused for P)
    __shared__ float redmax[2][4][32];
    __shared__ float redsum[2][4][32];
    __shared__ float alf[QBLK];

    const int t    = threadIdx.x;
    const int lane = t & 63;
    const int w    = t >> 6;
    const int l31  = lane & 31;
    const int hi   = lane >> 5;
    const int ksub = w & 3;
    const int qh   = w >> 2;

    const int krow = ksub * 32 + l31;
    const int qrow = qh * 32 + l31;
    const int kswz = (krow & 7) << 3;
    const int qswz = (qrow & 7) << 3;
    const int dcl  = ksub * 32 + l31;
    const int vswz = (dcl & 7) << 3;

    unsigned short* Plds = QR_[0];

    f32x16 O[NBAND];
    #pragma unroll
    for (int i = 0; i < NBAND; ++i)
        #pragma unroll
        for (int r = 0; r < 16; ++r) O[i][r] = 0.0f;

    float m_run = -INFINITY, l_run = 0.0f;

    #define QK_MMA(SLOT)                                                          \
    do {                                                                          \
        const unsigned short* Kb = Rr[SLOT];                                      \
        const unsigned short* Qb = QR_[SLOT];                                     \
        __builtin_amdgcn_s_setprio(1);                                            \
        _Pragma("unroll")                                                         \
        for (int kc = 0; kc < 8; ++kc) {                                          \
            const int d0 = kc * 16 + hi * 8;                                      \
            f16x8 a  = *(const f16x8*)&Kb[krow * 128 + (d0 ^ kswz)];              \
            f16x8 bq = *(const f16x8*)&Qb[qrow * 128 + (d0 ^ qswz)];              \
            C = __builtin_amdgcn_mfma_f32_32x32x16_f16(a, bq, C, 0, 0, 0);        \
        }                                                                         \
        __builtin_amdgcn_s_setprio(0);                                            \
    } while (0)

    #define PV_MMA(BAND, SLOT)                                                    \
    do {                                                                          \
        const unsigned short* Vb = Rr[SLOT];                                      \
        __builtin_amdgcn_s_setprio(1);                                            \
        _Pragma("unroll")                                                         \
        for (int kc = 0; kc < 8; ++kc) {                                          \
            const int kk0 = kc * 16 + hi * 8;                                     \
            f16x8 vb = *(const f16x8*)&Vb[dcl * 128 + (kk0 ^ vswz)];              \
            O[BAND] = __builtin_amdgcn_mfma_f32_32x32x16_f16(pa[kc], vb, O[BAND], 0, 0, 0); \
        }                                                                         \
        __builtin_amdgcn_s_setprio(0);                                            \
    } while (0)

    #pragma unroll 1
    for (int kb = 0; kb < NKB; ++kb) {
        const unsigned short* kt = kbase + (size_t)kb * 8 * TILE_US;

        f32x16 C;
        #pragma unroll
        for (int r = 0; r < 16; ++r) C[r] = 0.0f;

        // ---- prologue: chunks 0,1 in flight; chunk0 verified ----
        BAR();                                       // closes prev kb's phase-15 reads
        issue32(kt + 0 * TILE_US, Rr[0], w, lane);
        issue16(qbase + 0 * TILE_US, QR_[0], w, lane);
        issue32(kt + 1 * TILE_US, Rr[1], w, lane);
        issue16(qbase + 1 * TILE_US, QR_[1], w, lane);
        VMCNT(6);                                    // own chunk0 landed
        BAR();                                       // all waves' chunk0 landed

        // ---- QK phases 0..7 (compute chunk p from slot p%3) ----
        issue32(kt + 2 * TILE_US, Rr[2], w, lane);   // phase 0
        issue16(qbase + 2 * TILE_US, QR_[2], w, lane);
        VMCNT(6);
        QK_MMA(0);

        BAR();                                       // phase 1
        issue32(kt + 3 * TILE_US, Rr[0], w, lane);
        issue16(qbase + 3 * TILE_US, QR_[0], w, lane);
        VMCNT(6);
        QK_MMA(1);

        BAR();                                       // phase 2
        issue32(kt + 4 * TILE_US, Rr[1], w, lane);
        issue16(qbase + 4 * TILE_US, QR_[1], w, lane);
        VMCNT(6);
        QK_MMA(2);

        BAR();                                       // phase 3
        issue32(kt + 5 * TILE_US, Rr[2], w, lane);
        issue16(qbase + 5 * TILE_US, QR_[2], w, lane);
        VMCNT(6);
        QK_MMA(0);

        BAR();                                       // phase 4
        issue32(kt + 6 * TILE_US, Rr[0], w, lane);
        issue16(qbase + 6 * TILE_US, QR_[0], w, lane);
        VMCNT(6);
        QK_MMA(1);

        BAR();                                       // phase 5
        issue32(kt + 7 * TILE_US, Rr[1], w, lane);
        issue16(qbase + 7 * TILE_US, QR_[1], w, lane);
        VMCNT(6);
        QK_MMA(2);

        BAR();                                       // phase 6: V0 prefetch starts
        issue32(vbase + (size_t)(0 * 16 + kb) * TILE_US, Rr[2], w, lane);
        VMCNT(4);                                    // chunk7 landed
        QK_MMA(0);

        BAR();                                       // phase 7
        issue32(vbase + (size_t)(1 * 16 + kb) * TILE_US, Rr[0], w, lane);
        VMCNT(4);                                    // V0 landed
        QK_MMA(1);

        // ---- online softmax (kept on __syncthreads; drains are ~1-phase-old V DMA) ----
        float rm = -INFINITY;
        #pragma unroll
        for (int r = 0; r < 16; ++r) rm = fmaxf(rm, C[r]);
        rm = fmaxf(rm, __shfl_xor(rm, 32));
        if (lane < 32) redmax[qh][ksub][l31] = rm;
        __syncthreads();

        const float bm = fmaxf(fmaxf(redmax[qh][0][l31], redmax[qh][1][l31]),
                               fmaxf(redmax[qh][2][l31], redmax[qh][3][l31]));
        const float mn = fmaxf(m_run, bm);
        const float al = __expf(m_run - mn);
        float p[16];
        float ps = 0.0f;
        #pragma unroll
        for (int r = 0; r < 16; ++r) { p[r] = __expf(C[r] - mn); ps += p[r]; }
        ps += __shfl_xor(ps, 32);
        if (lane < 32) {
            redsum[qh][ksub][l31] = ps;
            if (ksub == 0) alf[qh * 32 + l31] = al;
        }
        {   // P (fp16) -> LDS [q][k] (Plds aliases QR_[0]; Q chunk6 dead since phase 6)
            #pragma unroll
            for (int rp = 0; rp < 8; ++rp) {
                const int r  = rp * 2;
                const int kk = ksub * 32 + (r & 3) + 8 * (r >> 2) + 4 * hi;
                *(unsigned*)&Plds[qrow * KBLK + (kk ^ qswz)] = pk2(p[r], p[r + 1]);
            }
        }
        __syncthreads();

        const float bs = redsum[qh][0][l31] + redsum[qh][1][l31] +
                         redsum[qh][2][l31] + redsum[qh][3][l31];
        l_run = l_run * al + bs;
        m_run = mn;

        float alr[16];
        #pragma unroll
        for (int r = 0; r < 16; ++r)
            alr[r] = alf[qh * 32 + (r & 3) + 8 * (r >> 2) + 4 * hi];
        #pragma unroll
        for (int i = 0; i < NBAND; ++i)
            #pragma unroll
            for (int r = 0; r < 16; ++r) O[i][r] *= alr[r];

        f16x8 pa[8];
        #pragma unroll
        for (int kc = 0; kc < 8; ++kc) {
            const int kk0 = kc * 16 + hi * 8;
            pa[kc] = *(const f16x8*)&Plds[qrow * KBLK + (kk0 ^ qswz)];
        }

        // ---- PV phases 8..15 (band b from slot (8+b)%3) ----
        issue32(vbase + (size_t)(2 * 16 + kb) * TILE_US, Rr[1], w, lane);  // phase 8
        VMCNT(4);
        PV_MMA(0, 2);

        BAR();                                       // phase 9
        issue32(vbase + (size_t)(3 * 16 + kb) * TILE_US, Rr[2], w, lane);
        VMCNT(4);
        PV_MMA(1, 0);

        BAR();                                       // phase 10
        issue32(vbase + (size_t)(4 * 16 + kb) * TILE_US, Rr[0], w, lane);
        VMCNT(4);
        PV_MMA(2, 1);

        BAR();                                       // phase 11
        issue32(vbase + (size_t)(5 * 16 + kb) * TILE_US, Rr[1], w, lane);
        VMCNT(4);
        PV_MMA(3, 2);

        BAR();                                       // phase 12
        issue32(vbase + (size_t)(6 * 16 + kb) * TILE_US, Rr[2], w, lane);
        VMCNT(4);
        PV_MMA(4, 0);

        BAR();                                       // phase 13
        issue32(vbase + (size_t)(7 * 16 + kb) * TILE_US, Rr[0], w, lane);
        VMCNT(4);
        PV_MMA(5, 1);

        BAR();                                       // phase 14 (no issue)
        PV_MMA(6, 2);

        BAR();                                       // phase 15
        VMCNT(0);                                    // V7 landed (issued 2 phases ago)
        PV_MMA(7, 0);
    }

    // ---- epilogue: out = residual(Q) + O / l ----
    if (lane < 32 && ksub == 0) alf[qh * 32 + l31] = 1.0f / l_run;
    __syncthreads();
    #pragma unroll
    for (int r = 0; r < 16; ++r) {
        const int qr = qh * 32 + (r & 3) + 8 * (r >> 2) + 4 * hi;
        const float il = alf[qr];
        const size_t rowoff = (size_t)(q0 + qr) * DIM;
        #pragma unroll
        for (int band = 0; band < NBAND; ++band) {
            const int dcol = band * 128 + ksub * 32 + l31;
            Og[rowoff + dcol] = Qg[rowoff + dcol] + O[band][r] * il;
        }
    }
    #undef QK_MMA
    #undef PV_MMA
}

// ============ fallback (round-2 kernel, verbatim — used if ws too small) ============
__global__ __launch_bounds__(512, 2)
void coattn_fb(const float* __restrict__ Sp, const float* __restrict__ Dp,
               float* __restrict__ outp)
{
    const int s   = blockIdx.x;
    const int g   = (s & 7) | ((s >> 8) << 3);
    const int qb  = (s >> 3) & 31;
    const int dir = g >> 3;
    const int b   = g & 7;

    const float* Qg = (dir ? Sp : Dp) + (size_t)b * LSEQ * DIM;
    const float* Kg = (dir ? Dp : Sp) + (size_t)b * LSEQ * DIM;
    float* Og = outp + (size_t)dir * ((size_t)B_ * LSEQ * DIM) + (size_t)b * LSEQ * DIM;
    const int q0 = qb * QBLK;

    __shared__ unsigned short Klds[KBLK * 128];
    __shared__ unsigned short Qlds[QBLK * 128];
    __shared__ unsigned short Plds[QBLK * KBLK];
    __shared__ unsigned short Vlds[128 * KBLK];
    __shared__ float redmax[2][4][32];
    __shared__ float redsum[2][4][32];
    __shared__ float alf[QBLK];

    const int t    = threadIdx.x;
    const int lane = t & 63;
    const int w    = t >> 6;
    const int l31  = lane & 31;
    const int hi   = lane >> 5;
    const int ksub = w & 3;
    const int qh   = w >> 2;

    f32x16 O[NBAND];
    #pragma unroll
    for (int i = 0; i < NBAND; ++i)
        #pragma unroll
        for (int r = 0; r < 16; ++r) O[i][r] = 0.0f;

    float m_run = -INFINITY, l_run = 0.0f;

    const int srow = t >> 4;
    const int fcol = (t & 15) << 2;
    const int vmm  = t & 31;
    const int vkp0 = t >> 5;

    const int krow = ksub * 32 + l31;
    const int qrow = qh * 32 + l31;

    for (int kb = 0; kb < NKB; ++kb) {
        const int k0g = kb * KBLK;
        f32x16 C;
        #pragma unroll
        for (int r = 0; r < 16; ++r) C[r] = 0.0f;

        float4 kreg[8], qreg[4];
        #pragma unroll
        for (int pass = 0; pass < 4; ++pass)
            #pragma unroll
            for (int h = 0; h < 2; ++h)
                kreg[pass * 2 + h] = *(const float4*)(Kg + (size_t)(k0g + pass * 32 + srow) * DIM + fcol + h * 64);
        #pragma unroll
        for (int pass = 0; pass < 2; ++pass)
            #pragma unroll
            for (int h = 0; h < 2; ++h)
                qreg[pass * 2 + h] = *(const float4*)(Qg + (size_t)(q0 + pass * 32 + srow) * DIM + fcol + h * 64);

        #pragma unroll 1
        for (int dc = 0; dc < NDC; ++dc) {
            __syncthreads();
            #pragma unroll
            for (int pass = 0; pass < 4; ++pass)
                #pragma unroll
                for (int h = 0; h < 2; ++h) {
                    const int row = pass * 32 + srow;
                    const int d   = fcol + h * 64;
                    const float4 v = kreg[pass * 2 + h];
                    *(uint2*)&Klds[row * 128 + (d ^ ((row & 7) << 3))] =
                        make_uint2(pk2(v.x, v.y), pk2(v.z, v.w));
                }
            #pragma unroll
            for (int pass = 0; pass < 2; ++pass)
                #pragma unroll
                for (int h = 0; h < 2; ++h) {
                    const int row = pass * 32 + srow;
                    const int d   = fcol + h * 64;
                    const float4 v = qreg[pass * 2 + h];
                    *(uint2*)&Qlds[row * 128 + (d ^ ((row & 7) << 3))] =
                        make_uint2(pk2(v.x, v.y), pk2(v.z, v.w));
                }
            __syncthreads();
            if (dc + 1 < NDC) {
                const int dbase = (dc + 1) * 128;
                #pragma unroll
                for (int pass = 0; pass < 4; ++pass)
                    #pragma unroll
                    for (int h = 0; h < 2; ++h)
                        kreg[pass * 2 + h] = *(const float4*)(Kg + (size_t)(k0g + pass * 32 + srow) * DIM + dbase + fcol + h * 64);
                #pragma unroll
                for (int pass = 0; pass < 2; ++pass)
                    #pragma unroll
                    for (int h = 0; h < 2; ++h)
                        qreg[pass * 2 + h] = *(const float4*)(Qg + (size_t)(q0 + pass * 32 + srow) * DIM + dbase + fcol + h * 64);
            }
            #pragma unroll
            for (int kc = 0; kc < 8; ++kc) {
                const int d0 = kc * 16 + hi * 8;
                f16x8 a  = *(const f16x8*)&Klds[krow * 128 + (d0 ^ ((krow & 7) << 3))];
                f16x8 bq = *(const f16x8*)&Qlds[qrow * 128 + (d0 ^ ((qrow & 7) << 3))];
                C = __builtin_amdgcn_mfma_f32_32x32x16_f16(a, bq, C, 0, 0, 0);
            }
        }

        float rm = -INFINITY;
        #pragma unroll
        for (int r = 0; r < 16; ++r) rm = fmaxf(rm, C[r]);
        rm = fmaxf(rm, __shfl_xor(rm, 32));
        if (lane < 32) redmax[qh][ksub][l31] = rm;
        __syncthreads();

        const float bm = fmaxf(fmaxf(redmax[qh][0][l31], redmax[qh][1][l31]),
                               fmaxf(redmax[qh][2][l31], redmax[qh][3][l31]));
        const float mn = fmaxf(m_run, bm);
        const float al = __expf(m_run - mn);
        float p[16];
        float ps = 0.0f;
        #pragma unroll
        for (int r = 0; r < 16; ++r) { p[r] = __expf(C[r] - mn); ps += p[r]; }
        ps += __shfl_xor(ps, 32);
        if (lane < 32) {
            redsum[qh][ksub][l31] = ps;
            if (ksub == 0) alf[qh * 32 + l31] = al;
        }
        {
            #pragma unroll
            for (int rp = 0; rp < 8; ++rp) {
                const int r  = rp * 2;
                const int kk = ksub * 32 + (r & 3) + 8 * (r >> 2) + 4 * hi;
                *(unsigned*)&Plds[qrow * KBLK + (kk ^ ((qrow & 7) << 3))] = pk2(p[r], p[r + 1]);
            }
        }
        __syncthreads();

        const float bs = redsum[qh][0][l31] + redsum[qh][1][l31] +
                         redsum[qh][2][l31] + redsum[qh][3][l31];
        l_run = l_run * al + bs;
        m_run = mn;

        float alr[16];
        #pragma unroll
        for (int r = 0; r < 16; ++r)
            alr[r] = alf[qh * 32 + (r & 3) + 8 * (r >> 2) + 4 * hi];
        #pragma unroll
        for (int i = 0; i < NBAND; ++i)
            #pragma unroll
            for (int r = 0; r < 16; ++r) O[i][r] *= alr[r];

        f16x8 pa[8];
        #pragma unroll
        for (int kc = 0; kc < 8; ++kc) {
            const int kk0 = kc * 16 + hi * 8;
            pa[kc] = *(const f16x8*)&Plds[qrow * KBLK + (kk0 ^ ((qrow & 7) << 3))];
        }

        float4 v0s[4], v1s[4];
        #pragma unroll
        for (int pass = 0; pass < 4; ++pass) {
            const int kp = pass * 16 + vkp0;
            v0s[pass] = *(const float4*)(Kg + (size_t)(k0g + 2 * kp) * DIM + vmm * 4);
            v1s[pass] = *(const float4*)(Kg + (size_t)(k0g + 2 * kp + 1) * DIM + vmm * 4);
        }

        #pragma unroll
        for (int band = 0; band < NBAND; ++band) {
            __syncthreads();
            #pragma unroll
            for (int pass = 0; pass < 4; ++pass) {
                const int kp = pass * 16 + vkp0;
                const float* a0 = (const float*)&v0s[pass];
                const float* a1 = (const float*)&v1s[pass];
                #pragma unroll
                for (int j = 0; j < 4; ++j) {
                    const int dclw = vmm * 4 + j;
                    *(unsigned*)&Vlds[dclw * KBLK + ((2 * kp) ^ ((dclw & 7) << 3))] = pk2(a0[j], a1[j]);
                }
            }
            __syncthreads();
            if (band + 1 < NBAND) {
                const int cb = (band + 1) * 128;
                #pragma unroll
                for (int pass = 0; pass < 4; ++pass) {
                    const int kp = pass * 16 + vkp0;
                    v0s[pass] = *(const float4*)(Kg + (size_t)(k0g + 2 * kp) * DIM + cb + vmm * 4);
                    v1s[pass] = *(const float4*)(Kg + (size_t)(k0g + 2 * kp + 1) * DIM + cb + vmm * 4);
                }
            }
            const int dclr = ksub * 32 + l31;
            const int sw  = (dclr & 7) << 3;
            #pragma unroll
            for (int kc = 0; kc < 8; ++kc) {
                const int kk0 = kc * 16 + hi * 8;
                f16x8 vb = *(const f16x8*)&Vlds[dclr * KBLK + (kk0 ^ sw)];
                O[band] = __builtin_amdgcn_mfma_f32_32x32x16_f16(pa[kc], vb, O[band], 0, 0, 0);
            }
        }
    }

    if (lane < 32 && ksub == 0) alf[qh * 32 + l31] = 1.0f / l_run;
    __syncthreads();
    #pragma unroll
    for (int r = 0; r < 16; ++r) {
        const int qr = qh * 32 + (r & 3) + 8 * (r >> 2) + 4 * hi;
        const float il = alf[qr];
        const size_t rowoff = (size_t)(q0 + qr) * DIM;
        #pragma unroll
        for (int band = 0; band < NBAND; ++band) {
            const int dcol = band * 128 + ksub * 32 + l31;
            Og[rowoff + dcol] = Qg[rowoff + dcol] + O[band][r] * il;
        }
    }
}

extern "C" void kernel_launch(void* const* d_in, const int* in_sizes, int n_in,
                              void* d_out, int out_size, void* d_ws, size_t ws_size,
                              hipStream_t stream) {
    const float* S = (const float*)d_in[0];
    const float* D = (const float*)d_in[1];
    float* out = (float*)d_out;
    if (ws_size >= WS_NEED) {
        unsigned short* Kimg = (unsigned short*)d_ws;
        unsigned short* Vimg = Kimg + KIMG_US;
        prepass<<<dim3(2048, 1, 1), dim3(256, 1, 1), 0, stream>>>(S, D, Kimg, Vimg);
        coattn_main<<<dim3(512, 1, 1), dim3(512, 1, 1), 0, stream>>>(S, D, out, Kimg, Vimg);
    } else {
        coattn_fb<<<dim3(512, 1, 1), dim3(512, 1, 1), 0, stream>>>(S, D, out);
    }
}